// Round 8
// baseline (204.805 us; speedup 1.0000x reference)
//
#include <hip/hip_runtime.h>

// B=131072, P=3, D=128, H=4, DH=32 ; fp32 in/out.
// Round 8: kill the staging phase + raise blocks/CU 3->4.
//   - A-fragments loaded DIRECTLY global->reg (each wave reads 16 full cache
//     lines per load instr; re-reads across 4 waves hit L1/L2). No x LDS, no
//     stage barrier: 2 barriers/block total.
//   - LDS split: kv[48][264] (k cols 0..127, v cols 128..255) 25.3 KB +
//     qz[48][136] (q, then z in-place) 13 KB = 38.4 KB -> 4 blocks/CU.
//   - q=0 shortcut: causal P=3 softmax row 0 is [1,0,0] -> z(0)=v(0) copy.
//   - plain fp32 out stores (r3/r7: L2 write-back merges; NT stores amplify).
// mfma_f32_16x16x32_bf16: A: lane l holds A[l&15][(l>>4)*8+j];
//   B: lane l holds B[(l>>4)*8+j][l&15]; C/D: col=l&15, row=(l>>4)*4+reg.

typedef __attribute__((ext_vector_type(8))) __bf16 bf16x8;
typedef __attribute__((ext_vector_type(4))) float f32x4;
typedef __attribute__((ext_vector_type(8))) unsigned short u16x8;

#define BATCH 131072
#define PP 3
#define DD 128
#define RB 48            // rows per block = 16 batches * 3
#define BB 16
#define THREADS 256
#define KV_STRIDE 264    // u16; k at col 0, v at col 128
#define QZ_STRIDE 136    // u16; q then z in-place

#define NFRAG_QKV (24 * 4)
#define NFRAG_WO (8 * 4)
#define QKV_PACK_ELEMS (NFRAG_QKV * 64 * 8)   // 49152 bf16
#define WO_PACK_ELEMS (NFRAG_WO * 64 * 8)     // 16384 bf16

__device__ __forceinline__ unsigned short f2bf(float f) {
    union { __bf16 h; unsigned short u; } c;
    c.h = (__bf16)f;                      // native RNE (v_cvt_pk_bf16_f32)
    return c.u;
}
__device__ __forceinline__ float bf2f(unsigned short s) {
    return __uint_as_float(((unsigned int)s) << 16);
}
__device__ __forceinline__ bf16x8 cvt8(float4 lo, float4 hi) {
    bf16x8 r;
    r[0] = (__bf16)lo.x; r[1] = (__bf16)lo.y; r[2] = (__bf16)lo.z; r[3] = (__bf16)lo.w;
    r[4] = (__bf16)hi.x; r[5] = (__bf16)hi.y; r[6] = (__bf16)hi.z; r[7] = (__bf16)hi.w;
    return r;
}

// ---- weight pre-pack --------------------------------------------------------
__global__ __launch_bounds__(256)
void pack_weights(const float* __restrict__ Wk, const float* __restrict__ Wq,
                  const float* __restrict__ Wv, const float* __restrict__ Wo,
                  unsigned short* __restrict__ pk)
{
    int e = blockIdx.x * 256 + threadIdx.x;     // 0 .. 65535
    int j = e & 7;
    int lane = (e >> 3) & 63;
    int lr = lane & 15, g = lane >> 4;
    float v;
    if (e < QKV_PACK_ELEMS) {
        int ks = (e >> 9) & 3;
        int nt = e >> 11;                        // 0..23
        int n = nt * 16 + lr;                    // 0..127 k, 128..255 q, 256..383 v
        int k = ks * 32 + g * 8 + j;
        const float* base = (n < 128) ? Wk : (n < 256 ? Wq : Wv);
        v = base[(size_t)(n & 127) * DD + k];
    } else {
        int e2 = e - QKV_PACK_ELEMS;
        int ks = (e2 >> 9) & 3;
        int nt = e2 >> 11;                       // 0..7
        int d = nt * 16 + lr;
        int f = ks * 32 + g * 8 + j;
        v = Wo[(size_t)d * DD + f];
    }
    pk[e] = f2bf(v);
}

// ---- fused attention --------------------------------------------------------
__global__ __launch_bounds__(THREADS, 4)
void attn_mfma(const float* __restrict__ x,
               const unsigned short* __restrict__ wpk,
               float* __restrict__ out)
{
    __shared__ unsigned short kv[RB * KV_STRIDE];  // 25344 B
    __shared__ unsigned short qz[RB * QZ_STRIDE];  // 13056 B

    const int t = threadIdx.x;
    const int wave = t >> 6, lane = t & 63;
    const int lr = lane & 15, g = lane >> 4;
    const size_t row0 = (size_t)blockIdx.x * RB;

    // ---- A-fragments straight from global (16 full cache lines / load instr)
    bf16x8 a[3][4];
    {
        const float* xb = x + row0 * DD;
        #pragma unroll
        for (int m = 0; m < 3; ++m)
            #pragma unroll
            for (int k = 0; k < 4; ++k) {
                const float4* p = (const float4*)(xb + (m * 16 + lr) * DD + k * 32 + g * 8);
                float4 lo = p[0];
                float4 hi = p[1];
                a[m][k] = cvt8(lo, hi);
            }
    }

    // ---- Phase A: qkv = x @ W^T ; wave owns n-tiles wave*6 .. wave*6+5.
    // nt<8 -> k into kv[.][nt*16+..]; 8..15 -> q into qz; 16..23 -> v into kv[.][128+..]
    {
        const bf16x8* bp = (const bf16x8*)wpk;    // frag (nt*4+k)*64+lane
        const int ntb = wave * 6;
        bf16x8 bcur[4], bnxt[4];
        #pragma unroll
        for (int k = 0; k < 4; ++k) bcur[k] = bp[(ntb * 4 + k) * 64 + lane];

        const f32x4 zero4 = {0.f, 0.f, 0.f, 0.f};
        #pragma unroll
        for (int n6 = 0; n6 < 6; ++n6) {
            int nt = ntb + n6;
            if (n6 < 5) {
                #pragma unroll
                for (int k = 0; k < 4; ++k) bnxt[k] = bp[((nt + 1) * 4 + k) * 64 + lane];
            }
            f32x4 acc[3];
            #pragma unroll
            for (int m = 0; m < 3; ++m) acc[m] = zero4;
            #pragma unroll
            for (int k = 0; k < 4; ++k)
                #pragma unroll
                for (int m = 0; m < 3; ++m)
                    acc[m] = __builtin_amdgcn_mfma_f32_16x16x32_bf16(a[m][k], bcur[k], acc[m], 0, 0, 0);

            unsigned short* dst;
            int stride, colbase;
            if (nt < 8)       { dst = kv; stride = KV_STRIDE; colbase = nt * 16; }
            else if (nt < 16) { dst = qz; stride = QZ_STRIDE; colbase = (nt - 8) * 16; }
            else              { dst = kv; stride = KV_STRIDE; colbase = 128 + (nt - 16) * 16; }
            #pragma unroll
            for (int m = 0; m < 3; ++m)
                #pragma unroll
                for (int r = 0; r < 4; ++r)
                    dst[(m * 16 + g * 4 + r) * stride + colbase + lr] = f2bf(acc[m][r]);

            if (n6 < 5) {
                #pragma unroll
                for (int k = 0; k < 4; ++k) bcur[k] = bnxt[k];
            }
        }
    }
    __syncthreads();

    // ---- Phase B: causal attention, thread per (batch, head, qpos): 192 threads.
    // q=0: softmax == [1,0,0] -> z = v(0), pure copy. z -> own qz slot.
    if (t < BB * 4 * PP) {
        const int lb = t / 12;
        const int rem = t % 12;
        const int hd = rem / 3;
        const int q = rem % 3;
        const int rq = lb * 3 + q;
        const int co = hd * 32;

        if (q == 0) {
            #pragma unroll
            for (int c = 0; c < 4; ++c) {
                u16x8 u = *(const u16x8*)&kv[rq * KV_STRIDE + 128 + co + c * 8];
                *(u16x8*)&qz[rq * QZ_STRIDE + co + c * 8] = u;
            }
        } else {
            float qv[32];
            #pragma unroll
            for (int c = 0; c < 4; ++c) {
                u16x8 u = *(const u16x8*)&qz[rq * QZ_STRIDE + co + c * 8];
                #pragma unroll
                for (int j = 0; j < 8; ++j) qv[c * 8 + j] = bf2f(u[j]);
            }
            float sc[3];
            float mx = -1e30f;
            #pragma unroll
            for (int p = 0; p < 3; ++p) {
                if (p <= q) {
                    float s = 0.f;
                    #pragma unroll
                    for (int c = 0; c < 4; ++c) {
                        u16x8 u = *(const u16x8*)&kv[(lb * 3 + p) * KV_STRIDE + co + c * 8];
                        #pragma unroll
                        for (int j = 0; j < 8; ++j) s += bf2f(u[j]) * qv[c * 8 + j];
                    }
                    s *= 0.17677669529663687f;    // 1/sqrt(32)
                    sc[p] = s;
                    mx = fmaxf(mx, s);
                }
            }
            float l = 0.f;
            #pragma unroll
            for (int p = 0; p < 3; ++p)
                if (p <= q) { sc[p] = __expf(sc[p] - mx); l += sc[p]; }
            const float inv = 1.f / l;

            #pragma unroll
            for (int c = 0; c < 4; ++c) {
                float z[8];
                #pragma unroll
                for (int j = 0; j < 8; ++j) z[j] = 0.f;
                #pragma unroll
                for (int p = 0; p < 3; ++p) {
                    if (p <= q) {
                        u16x8 u = *(const u16x8*)&kv[(lb * 3 + p) * KV_STRIDE + 128 + co + c * 8];
                        #pragma unroll
                        for (int j = 0; j < 8; ++j) z[j] += sc[p] * bf2f(u[j]);
                    }
                }
                u16x8 o;
                #pragma unroll
                for (int j = 0; j < 8; ++j) o[j] = f2bf(z[j] * inv);
                *(u16x8*)&qz[rq * QZ_STRIDE + co + c * 8] = o;   // own slot
            }
        }
    }
    __syncthreads();

    // ---- Phase C: out[48][128] = z @ Wo^T  (wave owns 2 n-tiles)
    {
        bf16x8 az[3][4];
        #pragma unroll
        for (int m = 0; m < 3; ++m)
            #pragma unroll
            for (int k = 0; k < 4; ++k)
                az[m][k] = *(const bf16x8*)&qz[(m * 16 + lr) * QZ_STRIDE + k * 32 + g * 8];

        const bf16x8* wop = (const bf16x8*)(wpk + QKV_PACK_ELEMS);
        const f32x4 zero4 = {0.f, 0.f, 0.f, 0.f};
        #pragma unroll
        for (int n2 = 0; n2 < 2; ++n2) {
            int nt = wave * 2 + n2;
            bf16x8 b[4];
            #pragma unroll
            for (int k = 0; k < 4; ++k) b[k] = wop[(nt * 4 + k) * 64 + lane];
            f32x4 acc[3];
            #pragma unroll
            for (int m = 0; m < 3; ++m) acc[m] = zero4;
            #pragma unroll
            for (int k = 0; k < 4; ++k)
                #pragma unroll
                for (int m = 0; m < 3; ++m)
                    acc[m] = __builtin_amdgcn_mfma_f32_16x16x32_bf16(az[m][k], b[k], acc[m], 0, 0, 0);
            #pragma unroll
            for (int m = 0; m < 3; ++m)
                #pragma unroll
                for (int r = 0; r < 4; ++r) {
                    size_t rg = row0 + (size_t)(m * 16 + g * 4 + r);
                    out[rg * DD + nt * 16 + lr] = acc[m][r];   // L2 write-back merges
                }
        }
    }
}

extern "C" void kernel_launch(void* const* d_in, const int* in_sizes, int n_in,
                              void* d_out, int out_size, void* d_ws, size_t ws_size,
                              hipStream_t stream) {
    const float* x  = (const float*)d_in[0];
    const float* Wk = (const float*)d_in[1];
    const float* Wq = (const float*)d_in[2];
    const float* Wv = (const float*)d_in[3];
    const float* Wo = (const float*)d_in[4];
    float* out = (float*)d_out;
    unsigned short* pk = (unsigned short*)d_ws;   // needs 131072 B

    pack_weights<<<(QKV_PACK_ELEMS + WO_PACK_ELEMS) / 256, 256, 0, stream>>>(Wk, Wq, Wv, Wo, pk);

    const int grid = BATCH * PP / RB;   // 8192
    attn_mfma<<<grid, THREADS, 0, stream>>>(x, pk, out);
}